// Round 1
// baseline (29927.936 us; speedup 1.0000x reference)
//
#include <hip/hip_runtime.h>
#include <math.h>

// Problem dims
#define SLEN 256
#define BSZ  128
#define DIN  128
#define HSZ  512
#define HH2  1024
#define GG3  1536
#define OSZ  25
#define NWG  128

typedef _Float16 h8 __attribute__((ext_vector_type(8)));
typedef float    f4 __attribute__((ext_vector_type(4)));

struct P_t {
  const float *x, *noise, *b_cin, *b1, *b2, *b3, *w4, *b4, *b_ih, *b_hh, *w_out, *b_out;
  _Float16 *WT1, *WT2, *WT3, *WTih, *WThh, *WTcin;   // row-major [N][K] (setup)
  _Float16 *FW1, *FW2, *FW3, *FWih, *FWhh;           // fragment-major (hot path)
  _Float16 *CIN, *COMlo, *Z1, *Z2, *HF16;
  float *LOGI, *GX, *PART, *HGRU;
  float *CF[2], *HF[2], *NF[2];                      // ping-pong state (state after step s in buf[s&1])
  int   *BAR;
  float *out;
};

__device__ __forceinline__ f4 mfma16(h8 a, h8 b, f4 c) {
  return __builtin_amdgcn_mfma_f32_16x16x32_f16(a, b, c, 0, 0, 0);
}

// Device-scope sense barrier: cnt at BAR[0], generation at BAR[32] (separate lines).
// AGENT-scope acq_rel/acquire atomics emit the L2 writeback/invalidate required for
// cross-XCD visibility on gfx950 (per-XCD L2s are not coherent).
__device__ __forceinline__ void gbar(int* bar) {
  __syncthreads();                       // drains vmcnt/lgkmcnt for all waves of this WG
  if (threadIdx.x == 0) {
    int* cnt = bar;
    int* gen = bar + 32;
    int g = __hip_atomic_load(gen, __ATOMIC_RELAXED, __HIP_MEMORY_SCOPE_AGENT);
    int a = __hip_atomic_fetch_add(cnt, 1, __ATOMIC_ACQ_REL, __HIP_MEMORY_SCOPE_AGENT);
    if (a == NWG - 1) {
      __hip_atomic_store(cnt, 0, __ATOMIC_RELAXED, __HIP_MEMORY_SCOPE_AGENT);
      __hip_atomic_store(gen, g + 1, __ATOMIC_RELEASE, __HIP_MEMORY_SCOPE_AGENT);
    } else {
      while (__hip_atomic_load(gen, __ATOMIC_ACQUIRE, __HIP_MEMORY_SCOPE_AGENT) == g)
        __builtin_amdgcn_s_sleep(2);
    }
  }
  __syncthreads();
}

// ---------------- setup kernels (unchanged) ----------------
__global__ __launch_bounds__(256) void transpose_cvt(const float* __restrict__ src,
    _Float16* __restrict__ dst, int K, int N) {
  __shared__ float tl[32][33];
  int nt = N >> 5;
  int bx = blockIdx.x % nt, by = blockIdx.x / nt;
  int n0 = bx << 5, k0 = by << 5;
  int tx = threadIdx.x & 31, ty = threadIdx.x >> 5;
#pragma unroll
  for (int i = 0; i < 4; ++i) {
    int r = ty + (i << 3);
    tl[r][tx] = src[(size_t)(k0 + r) * N + n0 + tx];
  }
  __syncthreads();
#pragma unroll
  for (int i = 0; i < 4; ++i) {
    int r = ty + (i << 3);
    dst[(size_t)(n0 + r) * K + k0 + tx] = (_Float16)tl[tx][r];
  }
}

__global__ __launch_bounds__(512) void fragpack(const _Float16* __restrict__ src,
    _Float16* __restrict__ dst, int K) {
  int ct = blockIdx.x;
  int chunks = (K / 32) * 64;
  for (int idx = threadIdx.x; idx < chunks; idx += 512) {
    int i = idx >> 6, lane = idx & 63;
    int mlw = lane & 15, qw = lane >> 4;
    *(h8*)(dst + ((size_t)ct * (K / 32) + i) * 512 + (size_t)lane * 8) =
        *(const h8*)(src + ((size_t)ct * 16 + mlw) * K + i * 32 + qw * 8);
  }
}

__global__ __launch_bounds__(256) void cin_kernel(P_t P) {
  int tid = blockIdx.x * blockDim.x + threadIdx.x;
  if (tid < SLEN * BSZ) {
    float u = P.noise[tid];
    P.LOGI[tid] = logf(u) - log1pf(-u);
  }
  int gw = tid >> 6, lane = tid & 63;
  int nw = (gridDim.x * blockDim.x) >> 6;
  int ml = lane & 15, q = lane >> 4;
  const int MT = (SLEN * BSZ) / 16;
  for (int tt = gw; tt < MT * 8; tt += nw) {
    int mt = tt & (MT - 1), nt = tt / MT;
    int m0 = mt * 16, n0 = nt * 64;
    int m = m0 + ml, b = m & 127, s = m >> 7;
    const float* ap = P.x + ((size_t)b * SLEN + s) * DIN + q * 8;
    const _Float16* bp = P.WTcin + (size_t)(n0 + ml) * DIN + q * 8;
    f4 a0 = {0,0,0,0}, a1 = a0, a2 = a0, a3 = a0;
#pragma unroll
    for (int k = 0; k < DIN; k += 32) {
      f4 lo = *(const f4*)(ap + k);
      f4 hi = *(const f4*)(ap + k + 4);
      h8 av;
      av[0] = (_Float16)lo[0]; av[1] = (_Float16)lo[1];
      av[2] = (_Float16)lo[2]; av[3] = (_Float16)lo[3];
      av[4] = (_Float16)hi[0]; av[5] = (_Float16)hi[1];
      av[6] = (_Float16)hi[2]; av[7] = (_Float16)hi[3];
      a0 = mfma16(av, *(const h8*)(bp + k),            a0);
      a1 = mfma16(av, *(const h8*)(bp + 16*DIN + k),   a1);
      a2 = mfma16(av, *(const h8*)(bp + 32*DIN + k),   a2);
      a3 = mfma16(av, *(const h8*)(bp + 48*DIN + k),   a3);
    }
#pragma unroll
    for (int r = 0; r < 4; ++r) {
      int row = m0 + q * 4 + r;
      int c0 = n0 + ml;
      P.CIN[(size_t)row * HSZ + c0     ] = (_Float16)tanhf(a0[r] + P.b_cin[c0]);
      P.CIN[(size_t)row * HSZ + c0 + 16] = (_Float16)tanhf(a1[r] + P.b_cin[c0 + 16]);
      P.CIN[(size_t)row * HSZ + c0 + 32] = (_Float16)tanhf(a2[r] + P.b_cin[c0 + 32]);
      P.CIN[(size_t)row * HSZ + c0 + 48] = (_Float16)tanhf(a3[r] + P.b_cin[c0 + 48]);
    }
  }
}

__global__ __launch_bounds__(256) void init_kernel(P_t P) {
  int idx = blockIdx.x * 256 + threadIdx.x;
  if (idx < BSZ * HSZ) {
    P.CF[0][idx] = 0.f; P.CF[1][idx] = 0.f;
    P.HF[0][idx] = 0.f; P.HF[1][idx] = 0.f;
    P.HF16[idx] = (_Float16)0.f; P.COMlo[idx] = (_Float16)0.f;
  }
  if (idx < BSZ) { P.NF[0][idx] = 0.f; P.NF[1][idx] = 0.f; }
  if (idx < 64) P.BAR[idx] = 0;
}

// ---------------- persistent time-loop kernel ----------------
// 128 WGs x 256 thr (512 waves). Per step: 3 device barriers.
//  Stage A: update(t-1) [redundant per row-block, fresh c -> LDS] + z1(t)
//  Stage B: z2(t) + gx(t)
//  Stage C: z3(t)->PART + gh(t) as (r,z,n) col-triples with fused GRU gates -> HGRU
// Work mappings keep weight-column peers on one XCD (blockIdx strides 8/16/24).
__global__ __launch_bounds__(256) void loop_kernel(P_t P) {
  const int tid  = threadIdx.x;
  const int lane = tid & 63, wv = tid >> 6;
  const int ml   = lane & 15, q = lane >> 4;
  const int b    = blockIdx.x;
  const int gw   = b * 4 + wv;
  const int rt   = b >> 4, cg = b & 15;   // stage-A mapping: 8 row-blocks x 16 col-groups
  const int m0   = rt << 4;

  __shared__ _Float16 c_lds[16][520];     // +8 halves pad: 2-way LDS banking (free)
  __shared__ float sA[16], sNOM[16], sNN[16];

#pragma unroll 1
  for (int it = 0; it < SLEN; ++it) {
    // ---------------- Stage A ----------------
    if (it == 0) {
      for (int e = tid; e < 16 * 512; e += 256) c_lds[e >> 9][e & 511] = (_Float16)0.f;
    } else {
      const int s = it - 1;
      const float* CFo = P.CF[(s + 1) & 1];
      const float* HFo = P.HF[(s + 1) & 1];
      const float* NFo = P.NF[(s + 1) & 1];
      float* CFn = P.CF[s & 1];
      float* HFn = P.HF[s & 1];
      float* NFn = P.NF[s & 1];
      {
        int rl = tid >> 4, sg = tid & 15;
        int row = m0 + rl;
        float v = P.PART[(size_t)(sg * 4 + 0) * BSZ + row]
                + P.PART[(size_t)(sg * 4 + 1) * BSZ + row]
                + P.PART[(size_t)(sg * 4 + 2) * BSZ + row]
                + P.PART[(size_t)(sg * 4 + 3) * BSZ + row];
        v += __shfl_xor(v, 1); v += __shfl_xor(v, 2);
        v += __shfl_xor(v, 4); v += __shfl_xor(v, 8);
        if (sg == 0) {
          float lg = (v + P.b4[0] + P.LOGI[(size_t)s * BSZ + row]) * 10.0f;
          float al = 1.f / (1.f + expf(-lg));
          float om = 1.f - al;
          float no = NFo[row];
          float nn = no * om + 1.f;
          sA[rl] = al; sNOM[rl] = no * om; sNN[rl] = nn;
          if (cg == 0) NFn[row] = nn;
        }
      }
      __syncthreads();
      for (int e = tid; e < 16 * 512; e += 256) {
        int rl = e >> 9, col = e & 511;
        int row = m0 + rl;
        float al = sA[rl], nom = sNOM[rl], nn = sNN[rl];
        size_t go = (size_t)row * HSZ + col;
        float hg = P.HGRU[go];
        float ho = HFo[go];
        float co = CFo[go];
        float ci = (float)P.CIN[((size_t)s * BSZ + row) * HSZ + col];
        float hn = ho * (1.f - al) + al * hg;
        float cn = (co * nom + ci) / nn;
        c_lds[rl][col] = (_Float16)cn;
        if (cg == 0) {
          CFn[go] = cn; HFn[go] = hn;
          P.COMlo[go] = (_Float16)cn;
          P.HF16[go]  = (_Float16)hn;
        }
      }
    }
    __syncthreads();
    // z1 tile (rt, ct = cg*4+wv): K = [c (LDS) | cin (global)]
    {
      int ct  = (cg << 2) + wv;
      int col = (ct << 4) + ml;
      const _Float16* a1 = P.CIN + ((size_t)it * BSZ + m0 + ml) * HSZ + q * 8;
      const _Float16* bp = P.FW1 + (size_t)ct * 32 * 512 + (size_t)lane * 8;
      const _Float16* a0 = &c_lds[ml][q * 8];
      f4 acc = {0.f, 0.f, 0.f, 0.f};
#pragma unroll
      for (int k = 0; k < 16; ++k)
        acc = mfma16(*(const h8*)(a0 + k * 32), *(const h8*)(bp + (size_t)k * 512), acc);
#pragma unroll
      for (int k = 0; k < 16; ++k)
        acc = mfma16(*(const h8*)(a1 + k * 32), *(const h8*)(bp + (size_t)(16 + k) * 512), acc);
      float bia = P.b1[col];
#pragma unroll
      for (int j = 0; j < 4; ++j)
        P.Z1[(size_t)(m0 + q * 4 + j) * HH2 + col] = (_Float16)fmaxf(acc[j] + bia, 0.f);
    }
    gbar(P.BAR);

    // ---------------- Stage B: z2 + gx ----------------
    for (int item = gw; item < 1280; item += 512) {
      if (item < 512) {
        int ct2 = item & 63, rt2 = item >> 6;     // ct-peers stride 16 WGs -> same XCD
        int m2 = rt2 << 4, col = (ct2 << 4) + ml;
        const _Float16* a0 = P.Z1 + (size_t)(m2 + ml) * HH2 + q * 8;
        const _Float16* bp = P.FW2 + (size_t)ct2 * 32 * 512 + (size_t)lane * 8;
        f4 acc = {0.f, 0.f, 0.f, 0.f};
#pragma unroll
        for (int k = 0; k < 32; ++k)
          acc = mfma16(*(const h8*)(a0 + k * 32), *(const h8*)(bp + (size_t)k * 512), acc);
        float bia = P.b2[col];
#pragma unroll
        for (int j = 0; j < 4; ++j)
          P.Z2[(size_t)(m2 + q * 4 + j) * HH2 + col] = (_Float16)fmaxf(acc[j] + bia, 0.f);
      } else {
        int u = item - 512;
        int ct2 = u % 96, rt2 = u / 96;           // ct-peers stride 24 WGs -> same XCD
        int m2 = rt2 << 4, col = (ct2 << 4) + ml;
        const _Float16* a0 = P.COMlo + (size_t)(m2 + ml) * HSZ + q * 8;
        const _Float16* bp = P.FWih + (size_t)ct2 * 16 * 512 + (size_t)lane * 8;
        f4 acc = {0.f, 0.f, 0.f, 0.f};
#pragma unroll
        for (int k = 0; k < 16; ++k)
          acc = mfma16(*(const h8*)(a0 + k * 32), *(const h8*)(bp + (size_t)k * 512), acc);
        float bia = P.b_ih[col];
#pragma unroll
        for (int j = 0; j < 4; ++j)
          P.GX[(size_t)(m2 + q * 4 + j) * GG3 + col] = acc[j] + bia;
      }
    }
    gbar(P.BAR);

    // ---------------- Stage C: z3->PART + gh (fused GRU gates) -> HGRU ----------------
    {
      const float* HFo = P.HF[(it + 1) & 1];   // h(it-1)
      for (int item = gw; item < 768; item += 512) {
        if (item < 512) {
          int ct3 = item & 63, rt3 = item >> 6;
          int m3 = rt3 << 4, col = (ct3 << 4) + ml;
          const _Float16* a0 = P.Z2 + (size_t)(m3 + ml) * HH2 + q * 8;
          const _Float16* bp = P.FW3 + (size_t)ct3 * 32 * 512 + (size_t)lane * 8;
          f4 acc = {0.f, 0.f, 0.f, 0.f};
#pragma unroll
          for (int k = 0; k < 32; ++k)
            acc = mfma16(*(const h8*)(a0 + k * 32), *(const h8*)(bp + (size_t)k * 512), acc);
          float bia = P.b3[col], w4v = P.w4[col];
#pragma unroll
          for (int j = 0; j < 4; ++j) {
            float v = fmaxf(acc[j] + bia, 0.f) * w4v;
            v += __shfl_xor(v, 1); v += __shfl_xor(v, 2);
            v += __shfl_xor(v, 4); v += __shfl_xor(v, 8);
            if (ml == 0) P.PART[(size_t)ct3 * BSZ + m3 + q * 4 + j] = v;
          }
        } else {
          int u = item - 512;                     // 0..255
          int tc = u & 31, rt3 = u >> 5;          // tc-peers stride 8 WGs -> same XCD
          int m3 = rt3 << 4, colr = (tc << 4) + ml;
          const _Float16* a0  = P.HF16 + (size_t)(m3 + ml) * HSZ + q * 8;
          const _Float16* bpr = P.FWhh + (size_t)tc * 16 * 512 + (size_t)lane * 8;
          const _Float16* bpz = P.FWhh + (size_t)(tc + 32) * 16 * 512 + (size_t)lane * 8;
          const _Float16* bpn = P.FWhh + (size_t)(tc + 64) * 16 * 512 + (size_t)lane * 8;
          f4 ar = {0.f, 0.f, 0.f, 0.f}, az = ar, an = ar;
#pragma unroll
          for (int k = 0; k < 16; ++k) {
            h8 av = *(const h8*)(a0 + k * 32);
            ar = mfma16(av, *(const h8*)(bpr + (size_t)k * 512), ar);
            az = mfma16(av, *(const h8*)(bpz + (size_t)k * 512), az);
            an = mfma16(av, *(const h8*)(bpn + (size_t)k * 512), an);
          }
          float bhr = P.b_hh[colr], bhz = P.b_hh[colr + 512], bhn = P.b_hh[colr + 1024];
#pragma unroll
          for (int j = 0; j < 4; ++j) {
            int row = m3 + q * 4 + j;
            size_t g3 = (size_t)row * GG3 + colr;
            float xr = P.GX[g3], xz = P.GX[g3 + 512], xn = P.GX[g3 + 1024];
            float rg = 1.f / (1.f + expf(-(xr + ar[j] + bhr)));
            float zg = 1.f / (1.f + expf(-(xz + az[j] + bhz)));
            float ng = tanhf(xn + rg * (an[j] + bhn));
            float ho = HFo[(size_t)row * HSZ + colr];
            P.HGRU[(size_t)row * HSZ + colr] = (1.f - zg) * ng + zg * ho;
          }
        }
      }
    }
    gbar(P.BAR);
  }

  // ---------------- Epilogue ----------------
  // E1: update(255) -> c(255) f16 (COMlo), h(255) f16/f32
  {
    const int s = SLEN - 1;
    const float* CFo = P.CF[(s + 1) & 1];
    const float* HFo = P.HF[(s + 1) & 1];
    const float* NFo = P.NF[(s + 1) & 1];
    float* HFn = P.HF[s & 1];
    {
      int rl = tid >> 4, sg = tid & 15;
      int row = m0 + rl;
      float v = P.PART[(size_t)(sg * 4 + 0) * BSZ + row]
              + P.PART[(size_t)(sg * 4 + 1) * BSZ + row]
              + P.PART[(size_t)(sg * 4 + 2) * BSZ + row]
              + P.PART[(size_t)(sg * 4 + 3) * BSZ + row];
      v += __shfl_xor(v, 1); v += __shfl_xor(v, 2);
      v += __shfl_xor(v, 4); v += __shfl_xor(v, 8);
      if (sg == 0) {
        float lg = (v + P.b4[0] + P.LOGI[(size_t)s * BSZ + row]) * 10.0f;
        float al = 1.f / (1.f + expf(-lg));
        float om = 1.f - al;
        float no = NFo[row];
        sA[rl] = al; sNOM[rl] = no * om; sNN[rl] = no * om + 1.f;
      }
    }
    __syncthreads();
    if (cg == 0) {
      for (int e = tid; e < 16 * 512; e += 256) {
        int rl = e >> 9, col = e & 511;
        int row = m0 + rl;
        size_t go = (size_t)row * HSZ + col;
        float al = sA[rl];
        float hn = HFo[go] * (1.f - al) + al * P.HGRU[go];
        float cn = (CFo[go] * sNOM[rl]
                    + (float)P.CIN[((size_t)s * BSZ + row) * HSZ + col]) / sNN[rl];
        HFn[go] = hn;
        P.HF16[go]  = (_Float16)hn;
        P.COMlo[go] = (_Float16)cn;
      }
    }
  }
  gbar(P.BAR);

  // E2: GX = c(255) @ W_ih + b_ih
  for (int item = gw; item < 768; item += 512) {
    int ct2 = item % 96, rt2 = item / 96;
    int m2 = rt2 << 4, col = (ct2 << 4) + ml;
    const _Float16* a0 = P.COMlo + (size_t)(m2 + ml) * HSZ + q * 8;
    const _Float16* bp = P.FWih + (size_t)ct2 * 16 * 512 + (size_t)lane * 8;
    f4 acc = {0.f, 0.f, 0.f, 0.f};
#pragma unroll
    for (int k = 0; k < 16; ++k)
      acc = mfma16(*(const h8*)(a0 + k * 32), *(const h8*)(bp + (size_t)k * 512), acc);
    float bia = P.b_ih[col];
#pragma unroll
    for (int j = 0; j < 4; ++j)
      P.GX[(size_t)(m2 + q * 4 + j) * GG3 + col] = acc[j] + bia;
  }
  gbar(P.BAR);

  // E3: gh triples -> h_fin into HGRU
  {
    const float* HFo = P.HF[(SLEN - 1) & 1];   // h(255)
    for (int item = gw; item < 256; item += 512) {
      int tc = item & 31, rt3 = item >> 5;
      int m3 = rt3 << 4, colr = (tc << 4) + ml;
      const _Float16* a0  = P.HF16 + (size_t)(m3 + ml) * HSZ + q * 8;
      const _Float16* bpr = P.FWhh + (size_t)tc * 16 * 512 + (size_t)lane * 8;
      const _Float16* bpz = P.FWhh + (size_t)(tc + 32) * 16 * 512 + (size_t)lane * 8;
      const _Float16* bpn = P.FWhh + (size_t)(tc + 64) * 16 * 512 + (size_t)lane * 8;
      f4 ar = {0.f, 0.f, 0.f, 0.f}, az = ar, an = ar;
#pragma unroll
      for (int k = 0; k < 16; ++k) {
        h8 av = *(const h8*)(a0 + k * 32);
        ar = mfma16(av, *(const h8*)(bpr + (size_t)k * 512), ar);
        az = mfma16(av, *(const h8*)(bpz + (size_t)k * 512), az);
        an = mfma16(av, *(const h8*)(bpn + (size_t)k * 512), an);
      }
      float bhr = P.b_hh[colr], bhz = P.b_hh[colr + 512], bhn = P.b_hh[colr + 1024];
#pragma unroll
      for (int j = 0; j < 4; ++j) {
        int row = m3 + q * 4 + j;
        size_t g3 = (size_t)row * GG3 + colr;
        float xr = P.GX[g3], xz = P.GX[g3 + 512], xn = P.GX[g3 + 1024];
        float rg = 1.f / (1.f + expf(-(xr + ar[j] + bhr)));
        float zg = 1.f / (1.f + expf(-(xz + az[j] + bhz)));
        float ng = tanhf(xn + rg * (an[j] + bhn));
        float ho = HFo[(size_t)row * HSZ + colr];
        P.HGRU[(size_t)row * HSZ + colr] = (1.f - zg) * ng + zg * ho;
      }
    }
  }
  gbar(P.BAR);

  // E4: out[row b] = h_fin @ w_out + b_out
  {
    __shared__ float hfl[512];
    const float* hsrc = P.HGRU + (size_t)b * HSZ;
    for (int e = tid; e < 512; e += 256) hfl[e] = hsrc[e];
    __syncthreads();
    for (int c2 = wv; c2 < OSZ; c2 += 4) {
      float v = 0.f;
#pragma unroll
      for (int j = 0; j < 8; ++j)
        v += hfl[lane + 64 * j] * P.w_out[(size_t)(lane + 64 * j) * OSZ + c2];
      for (int off = 32; off > 0; off >>= 1) v += __shfl_xor(v, off);
      if (lane == 0) P.out[b * OSZ + c2] = v + P.b_out[c2];
    }
  }
}

// ---------------- host ----------------
extern "C" void kernel_launch(void* const* d_in, const int* in_sizes, int n_in,
                              void* d_out, int out_size, void* d_ws, size_t ws_size,
                              hipStream_t stream) {
  const float* x     = (const float*)d_in[0];
  const float* noise = (const float*)d_in[1];
  const float* w_cin = (const float*)d_in[2];
  const float* b_cin = (const float*)d_in[3];
  const float* w1    = (const float*)d_in[4];
  const float* b1    = (const float*)d_in[5];
  const float* w2    = (const float*)d_in[6];
  const float* b2    = (const float*)d_in[7];
  const float* w3    = (const float*)d_in[8];
  const float* b3    = (const float*)d_in[9];
  const float* w4    = (const float*)d_in[10];
  const float* b4    = (const float*)d_in[11];
  const float* w_ih  = (const float*)d_in[12];
  const float* b_ih  = (const float*)d_in[13];
  const float* w_hh  = (const float*)d_in[14];
  const float* b_hh  = (const float*)d_in[15];
  const float* w_out = (const float*)d_in[16];
  const float* b_out = (const float*)d_in[17];

  char* ws = (char*)d_ws;
  size_t off = 0;
  auto alloc = [&](size_t bytes) -> void* {
    void* p = ws + off;
    off = (off + bytes + 255) & ~(size_t)255;
    return p;
  };

  P_t P;
  P.x = x; P.noise = noise; P.b_cin = b_cin; P.b1 = b1; P.b2 = b2; P.b3 = b3;
  P.w4 = w4; P.b4 = b4; P.b_ih = b_ih; P.b_hh = b_hh; P.w_out = w_out; P.b_out = b_out;
  P.WT1   = (_Float16*)alloc((size_t)HH2 * HH2 * 2);
  P.WT2   = (_Float16*)alloc((size_t)HH2 * HH2 * 2);
  P.WT3   = (_Float16*)alloc((size_t)HH2 * HH2 * 2);
  P.WTih  = (_Float16*)alloc((size_t)GG3 * HSZ * 2);
  P.WThh  = (_Float16*)alloc((size_t)GG3 * HSZ * 2);
  P.WTcin = (_Float16*)alloc((size_t)HSZ * DIN * 2);
  P.FW1   = (_Float16*)alloc((size_t)HH2 * HH2 * 2);
  P.FW2   = (_Float16*)alloc((size_t)HH2 * HH2 * 2);
  P.FW3   = (_Float16*)alloc((size_t)HH2 * HH2 * 2);
  P.FWih  = (_Float16*)alloc((size_t)GG3 * HSZ * 2);
  P.FWhh  = (_Float16*)alloc((size_t)GG3 * HSZ * 2);
  P.CIN   = (_Float16*)alloc((size_t)SLEN * BSZ * HSZ * 2);
  P.COMlo = (_Float16*)alloc((size_t)BSZ * HSZ * 2);
  P.Z1    = (_Float16*)alloc((size_t)BSZ * HH2 * 2);
  P.Z2    = (_Float16*)alloc((size_t)BSZ * HH2 * 2);
  P.HF16  = (_Float16*)alloc((size_t)BSZ * HSZ * 2);
  P.LOGI  = (float*)alloc((size_t)SLEN * BSZ * 4);
  P.GX    = (float*)alloc((size_t)BSZ * GG3 * 4);
  P.PART  = (float*)alloc((size_t)64 * BSZ * 4);
  P.HGRU  = (float*)alloc((size_t)BSZ * HSZ * 4);
  P.CF[0] = (float*)alloc((size_t)BSZ * HSZ * 4);
  P.CF[1] = (float*)alloc((size_t)BSZ * HSZ * 4);
  P.HF[0] = (float*)alloc((size_t)BSZ * HSZ * 4);
  P.HF[1] = (float*)alloc((size_t)BSZ * HSZ * 4);
  P.NF[0] = (float*)alloc((size_t)BSZ * 4);
  P.NF[1] = (float*)alloc((size_t)BSZ * 4);
  P.BAR   = (int*)alloc(64 * 4);
  P.out   = (float*)d_out;

  transpose_cvt<<<(HH2/32)*(HH2/32), 256, 0, stream>>>(w1, P.WT1, HH2, HH2);
  transpose_cvt<<<(HH2/32)*(HH2/32), 256, 0, stream>>>(w2, P.WT2, HH2, HH2);
  transpose_cvt<<<(HH2/32)*(HH2/32), 256, 0, stream>>>(w3, P.WT3, HH2, HH2);
  transpose_cvt<<<(GG3/32)*(HSZ/32), 256, 0, stream>>>(w_ih, P.WTih, HSZ, GG3);
  transpose_cvt<<<(GG3/32)*(HSZ/32), 256, 0, stream>>>(w_hh, P.WThh, HSZ, GG3);
  transpose_cvt<<<(HSZ/32)*(DIN/32), 256, 0, stream>>>(w_cin, P.WTcin, DIN, HSZ);
  fragpack<<<HH2/16, 512, 0, stream>>>(P.WT1, P.FW1, HH2);
  fragpack<<<HH2/16, 512, 0, stream>>>(P.WT2, P.FW2, HH2);
  fragpack<<<HH2/16, 512, 0, stream>>>(P.WT3, P.FW3, HH2);
  fragpack<<<GG3/16, 512, 0, stream>>>(P.WTih, P.FWih, HSZ);
  fragpack<<<GG3/16, 512, 0, stream>>>(P.WThh, P.FWhh, HSZ);

  cin_kernel<<<1024, 256, 0, stream>>>(P);
  init_kernel<<<256, 256, 0, stream>>>(P);

  loop_kernel<<<NWG, 256, 0, stream>>>(P);
}

// Round 2
// 15120.094 us; speedup vs baseline: 1.9793x; 1.9793x over previous
//
#include <hip/hip_runtime.h>
#include <math.h>

// Problem dims
#define SLEN 256
#define BSZ  128
#define DIN  128
#define HSZ  512
#define HH2  1024
#define GG3  1536
#define OSZ  25
#define NWG  128

typedef _Float16 h8 __attribute__((ext_vector_type(8)));
typedef float    f4 __attribute__((ext_vector_type(4)));

struct P_t {
  const float *x, *noise, *b_cin, *b1, *b2, *b3, *w4, *b4, *b_ih, *b_hh, *w_out, *b_out;
  _Float16 *WT1, *WT2, *WT3, *WTih, *WThh, *WTcin;   // row-major [N][K] (setup)
  _Float16 *FW1, *FW2, *FW3, *FWih, *FWhh;           // fragment-major (hot path)
  _Float16 *CIN, *COMlo, *Z1, *Z2, *HF16;
  float *LOGI, *GX, *PART, *HGRU;
  float *CF[2], *HF[2], *NF[2];                      // ping-pong state (state after step s in buf[s&1])
  int   *BAR;
  float *out;
};

__device__ __forceinline__ f4 mfma16(h8 a, h8 b, f4 c) {
  return __builtin_amdgcn_mfma_f32_16x16x32_f16(a, b, c, 0, 0, 0);
}

// Flag-gather device barrier (no contended RMW):
//  - gen lives at bar[0] (own line)
//  - WG b (b>=1) arrival flag at bar[b*16] (64B spacing, zero contention)
//  - WG0 wave0 gathers all flags with 2 lane-parallel RELAXED loads, acquire-fences
//    once, then release-stores gen. Pollers spin RELAXED (no invalidate per poll),
//    acquire-fence once on exit. RELEASE stores emit the L2 writeback needed for
//    cross-XCD visibility; RELAXED agent loads read the coherence point (sc1).
__device__ __forceinline__ void gbar(int* bar, int epoch) {
  __syncthreads();
  const int tid = threadIdx.x;
  if (blockIdx.x == 0) {
    if (tid < 64) {
      const int i0 = 1 + tid;          // flags 1..64
      const int i1 = 65 + tid;         // flags 65..127
      const bool has1 = (i1 < NWG);
      for (;;) {
        int f0 = __hip_atomic_load(bar + (size_t)i0 * 16, __ATOMIC_RELAXED, __HIP_MEMORY_SCOPE_AGENT);
        int f1 = has1 ? __hip_atomic_load(bar + (size_t)i1 * 16, __ATOMIC_RELAXED, __HIP_MEMORY_SCOPE_AGENT)
                      : epoch;
        if (__all(f0 == epoch && f1 == epoch)) break;
        __builtin_amdgcn_s_sleep(1);
      }
      __builtin_amdgcn_fence(__ATOMIC_ACQUIRE, "agent");
      if (tid == 0)
        __hip_atomic_store(bar, epoch, __ATOMIC_RELEASE, __HIP_MEMORY_SCOPE_AGENT);
    }
  } else {
    if (tid == 0) {
      __hip_atomic_store(bar + (size_t)blockIdx.x * 16, epoch, __ATOMIC_RELEASE, __HIP_MEMORY_SCOPE_AGENT);
      while (__hip_atomic_load(bar, __ATOMIC_RELAXED, __HIP_MEMORY_SCOPE_AGENT) < epoch)
        __builtin_amdgcn_s_sleep(1);
      __builtin_amdgcn_fence(__ATOMIC_ACQUIRE, "agent");
    }
  }
  __syncthreads();
}

// ---------------- setup kernels (unchanged) ----------------
__global__ __launch_bounds__(256) void transpose_cvt(const float* __restrict__ src,
    _Float16* __restrict__ dst, int K, int N) {
  __shared__ float tl[32][33];
  int nt = N >> 5;
  int bx = blockIdx.x % nt, by = blockIdx.x / nt;
  int n0 = bx << 5, k0 = by << 5;
  int tx = threadIdx.x & 31, ty = threadIdx.x >> 5;
#pragma unroll
  for (int i = 0; i < 4; ++i) {
    int r = ty + (i << 3);
    tl[r][tx] = src[(size_t)(k0 + r) * N + n0 + tx];
  }
  __syncthreads();
#pragma unroll
  for (int i = 0; i < 4; ++i) {
    int r = ty + (i << 3);
    dst[(size_t)(n0 + r) * K + k0 + tx] = (_Float16)tl[tx][r];
  }
}

__global__ __launch_bounds__(512) void fragpack(const _Float16* __restrict__ src,
    _Float16* __restrict__ dst, int K) {
  int ct = blockIdx.x;
  int chunks = (K / 32) * 64;
  for (int idx = threadIdx.x; idx < chunks; idx += 512) {
    int i = idx >> 6, lane = idx & 63;
    int mlw = lane & 15, qw = lane >> 4;
    *(h8*)(dst + ((size_t)ct * (K / 32) + i) * 512 + (size_t)lane * 8) =
        *(const h8*)(src + ((size_t)ct * 16 + mlw) * K + i * 32 + qw * 8);
  }
}

__global__ __launch_bounds__(256) void cin_kernel(P_t P) {
  int tid = blockIdx.x * blockDim.x + threadIdx.x;
  if (tid < SLEN * BSZ) {
    float u = P.noise[tid];
    P.LOGI[tid] = logf(u) - log1pf(-u);
  }
  int gw = tid >> 6, lane = tid & 63;
  int nw = (gridDim.x * blockDim.x) >> 6;
  int ml = lane & 15, q = lane >> 4;
  const int MT = (SLEN * BSZ) / 16;
  for (int tt = gw; tt < MT * 8; tt += nw) {
    int mt = tt & (MT - 1), nt = tt / MT;
    int m0 = mt * 16, n0 = nt * 64;
    int m = m0 + ml, b = m & 127, s = m >> 7;
    const float* ap = P.x + ((size_t)b * SLEN + s) * DIN + q * 8;
    const _Float16* bp = P.WTcin + (size_t)(n0 + ml) * DIN + q * 8;
    f4 a0 = {0,0,0,0}, a1 = a0, a2 = a0, a3 = a0;
#pragma unroll
    for (int k = 0; k < DIN; k += 32) {
      f4 lo = *(const f4*)(ap + k);
      f4 hi = *(const f4*)(ap + k + 4);
      h8 av;
      av[0] = (_Float16)lo[0]; av[1] = (_Float16)lo[1];
      av[2] = (_Float16)lo[2]; av[3] = (_Float16)lo[3];
      av[4] = (_Float16)hi[0]; av[5] = (_Float16)hi[1];
      av[6] = (_Float16)hi[2]; av[7] = (_Float16)hi[3];
      a0 = mfma16(av, *(const h8*)(bp + k),            a0);
      a1 = mfma16(av, *(const h8*)(bp + 16*DIN + k),   a1);
      a2 = mfma16(av, *(const h8*)(bp + 32*DIN + k),   a2);
      a3 = mfma16(av, *(const h8*)(bp + 48*DIN + k),   a3);
    }
#pragma unroll
    for (int r = 0; r < 4; ++r) {
      int row = m0 + q * 4 + r;
      int c0 = n0 + ml;
      P.CIN[(size_t)row * HSZ + c0     ] = (_Float16)tanhf(a0[r] + P.b_cin[c0]);
      P.CIN[(size_t)row * HSZ + c0 + 16] = (_Float16)tanhf(a1[r] + P.b_cin[c0 + 16]);
      P.CIN[(size_t)row * HSZ + c0 + 32] = (_Float16)tanhf(a2[r] + P.b_cin[c0 + 32]);
      P.CIN[(size_t)row * HSZ + c0 + 48] = (_Float16)tanhf(a3[r] + P.b_cin[c0 + 48]);
    }
  }
}

__global__ __launch_bounds__(256) void init_kernel(P_t P) {
  int idx = blockIdx.x * 256 + threadIdx.x;
  if (idx < BSZ * HSZ) {
    P.CF[0][idx] = 0.f; P.CF[1][idx] = 0.f;
    P.HF[0][idx] = 0.f; P.HF[1][idx] = 0.f;
    P.HF16[idx] = (_Float16)0.f; P.COMlo[idx] = (_Float16)0.f;
  }
  if (idx < BSZ) { P.NF[0][idx] = 0.f; P.NF[1][idx] = 0.f; }
  if (idx < 2048) P.BAR[idx] = 0;
}

// ---------------- persistent time-loop kernel ----------------
// 128 WGs x 256 thr (512 waves). Per step: 3 device barriers.
//  Stage A: update(t-1) [redundant per row-block, fresh c -> LDS] + z1(t)
//  Stage B: z2(t) + gx(t)
//  Stage C: z3(t)->PART + gh(t) as (r,z,n) col-triples with fused GRU gates -> HGRU
__global__ __launch_bounds__(256) void loop_kernel(P_t P) {
  const int tid  = threadIdx.x;
  const int lane = tid & 63, wv = tid >> 6;
  const int ml   = lane & 15, q = lane >> 4;
  const int b    = blockIdx.x;
  const int gw   = b * 4 + wv;
  const int rt   = b >> 4, cg = b & 15;   // stage-A mapping: 8 row-blocks x 16 col-groups
  const int m0   = rt << 4;

  __shared__ _Float16 c_lds[16][520];     // +8 halves pad
  __shared__ float sA[16], sNOM[16], sNN[16];

  int ep = 0;

#pragma unroll 1
  for (int it = 0; it < SLEN; ++it) {
    // ---------------- Stage A ----------------
    if (it == 0) {
      for (int e = tid; e < 16 * 512; e += 256) c_lds[e >> 9][e & 511] = (_Float16)0.f;
    } else {
      const int s = it - 1;
      const float* CFo = P.CF[(s + 1) & 1];
      const float* HFo = P.HF[(s + 1) & 1];
      const float* NFo = P.NF[(s + 1) & 1];
      float* CFn = P.CF[s & 1];
      float* HFn = P.HF[s & 1];
      float* NFn = P.NF[s & 1];
      {
        int rl = tid >> 4, sg = tid & 15;
        int row = m0 + rl;
        float v = P.PART[(size_t)(sg * 4 + 0) * BSZ + row]
                + P.PART[(size_t)(sg * 4 + 1) * BSZ + row]
                + P.PART[(size_t)(sg * 4 + 2) * BSZ + row]
                + P.PART[(size_t)(sg * 4 + 3) * BSZ + row];
        v += __shfl_xor(v, 1); v += __shfl_xor(v, 2);
        v += __shfl_xor(v, 4); v += __shfl_xor(v, 8);
        if (sg == 0) {
          float lg = (v + P.b4[0] + P.LOGI[(size_t)s * BSZ + row]) * 10.0f;
          float al = 1.f / (1.f + expf(-lg));
          float om = 1.f - al;
          float no = NFo[row];
          float nn = no * om + 1.f;
          sA[rl] = al; sNOM[rl] = no * om; sNN[rl] = nn;
          if (cg == 0) NFn[row] = nn;
        }
      }
      __syncthreads();
      for (int e = tid; e < 16 * 512; e += 256) {
        int rl = e >> 9, col = e & 511;
        int row = m0 + rl;
        float al = sA[rl], nom = sNOM[rl], nn = sNN[rl];
        size_t go = (size_t)row * HSZ + col;
        float hg = P.HGRU[go];
        float ho = HFo[go];
        float co = CFo[go];
        float ci = (float)P.CIN[((size_t)s * BSZ + row) * HSZ + col];
        float hn = ho * (1.f - al) + al * hg;
        float cn = (co * nom + ci) / nn;
        c_lds[rl][col] = (_Float16)cn;
        if (cg == 0) {
          CFn[go] = cn; HFn[go] = hn;
          P.COMlo[go] = (_Float16)cn;
          P.HF16[go]  = (_Float16)hn;
        }
      }
    }
    __syncthreads();
    // z1 tile (rt, ct = cg*4+wv): K = [c (LDS) | cin (global)]
    {
      int ct  = (cg << 2) + wv;
      int col = (ct << 4) + ml;
      const _Float16* a1 = P.CIN + ((size_t)it * BSZ + m0 + ml) * HSZ + q * 8;
      const _Float16* bp = P.FW1 + (size_t)ct * 32 * 512 + (size_t)lane * 8;
      const _Float16* a0 = &c_lds[ml][q * 8];
      f4 acc = {0.f, 0.f, 0.f, 0.f};
#pragma unroll
      for (int k = 0; k < 16; ++k)
        acc = mfma16(*(const h8*)(a0 + k * 32), *(const h8*)(bp + (size_t)k * 512), acc);
#pragma unroll
      for (int k = 0; k < 16; ++k)
        acc = mfma16(*(const h8*)(a1 + k * 32), *(const h8*)(bp + (size_t)(16 + k) * 512), acc);
      float bia = P.b1[col];
#pragma unroll
      for (int j = 0; j < 4; ++j)
        P.Z1[(size_t)(m0 + q * 4 + j) * HH2 + col] = (_Float16)fmaxf(acc[j] + bia, 0.f);
    }
    gbar(P.BAR, ++ep);

    // ---------------- Stage B: z2 + gx ----------------
    for (int item = gw; item < 1280; item += 512) {
      if (item < 512) {
        int ct2 = item & 63, rt2 = item >> 6;
        int m2 = rt2 << 4, col = (ct2 << 4) + ml;
        const _Float16* a0 = P.Z1 + (size_t)(m2 + ml) * HH2 + q * 8;
        const _Float16* bp = P.FW2 + (size_t)ct2 * 32 * 512 + (size_t)lane * 8;
        f4 acc = {0.f, 0.f, 0.f, 0.f};
#pragma unroll
        for (int k = 0; k < 32; ++k)
          acc = mfma16(*(const h8*)(a0 + k * 32), *(const h8*)(bp + (size_t)k * 512), acc);
        float bia = P.b2[col];
#pragma unroll
        for (int j = 0; j < 4; ++j)
          P.Z2[(size_t)(m2 + q * 4 + j) * HH2 + col] = (_Float16)fmaxf(acc[j] + bia, 0.f);
      } else {
        int u = item - 512;
        int ct2 = u % 96, rt2 = u / 96;
        int m2 = rt2 << 4, col = (ct2 << 4) + ml;
        const _Float16* a0 = P.COMlo + (size_t)(m2 + ml) * HSZ + q * 8;
        const _Float16* bp = P.FWih + (size_t)ct2 * 16 * 512 + (size_t)lane * 8;
        f4 acc = {0.f, 0.f, 0.f, 0.f};
#pragma unroll
        for (int k = 0; k < 16; ++k)
          acc = mfma16(*(const h8*)(a0 + k * 32), *(const h8*)(bp + (size_t)k * 512), acc);
        float bia = P.b_ih[col];
#pragma unroll
        for (int j = 0; j < 4; ++j)
          P.GX[(size_t)(m2 + q * 4 + j) * GG3 + col] = acc[j] + bia;
      }
    }
    gbar(P.BAR, ++ep);

    // ---------------- Stage C: z3->PART + gh (fused GRU gates) -> HGRU ----------------
    {
      const float* HFo = P.HF[(it + 1) & 1];   // h(it-1)
      for (int item = gw; item < 768; item += 512) {
        if (item < 512) {
          int ct3 = item & 63, rt3 = item >> 6;
          int m3 = rt3 << 4, col = (ct3 << 4) + ml;
          const _Float16* a0 = P.Z2 + (size_t)(m3 + ml) * HH2 + q * 8;
          const _Float16* bp = P.FW3 + (size_t)ct3 * 32 * 512 + (size_t)lane * 8;
          f4 acc = {0.f, 0.f, 0.f, 0.f};
#pragma unroll
          for (int k = 0; k < 32; ++k)
            acc = mfma16(*(const h8*)(a0 + k * 32), *(const h8*)(bp + (size_t)k * 512), acc);
          float bia = P.b3[col], w4v = P.w4[col];
#pragma unroll
          for (int j = 0; j < 4; ++j) {
            float v = fmaxf(acc[j] + bia, 0.f) * w4v;
            v += __shfl_xor(v, 1); v += __shfl_xor(v, 2);
            v += __shfl_xor(v, 4); v += __shfl_xor(v, 8);
            if (ml == 0) P.PART[(size_t)ct3 * BSZ + m3 + q * 4 + j] = v;
          }
        } else {
          int u = item - 512;                     // 0..255
          int tc = u & 31, rt3 = u >> 5;
          int m3 = rt3 << 4, colr = (tc << 4) + ml;
          const _Float16* a0  = P.HF16 + (size_t)(m3 + ml) * HSZ + q * 8;
          const _Float16* bpr = P.FWhh + (size_t)tc * 16 * 512 + (size_t)lane * 8;
          const _Float16* bpz = P.FWhh + (size_t)(tc + 32) * 16 * 512 + (size_t)lane * 8;
          const _Float16* bpn = P.FWhh + (size_t)(tc + 64) * 16 * 512 + (size_t)lane * 8;
          f4 ar = {0.f, 0.f, 0.f, 0.f}, az = ar, an = ar;
#pragma unroll
          for (int k = 0; k < 16; ++k) {
            h8 av = *(const h8*)(a0 + k * 32);
            ar = mfma16(av, *(const h8*)(bpr + (size_t)k * 512), ar);
            az = mfma16(av, *(const h8*)(bpz + (size_t)k * 512), az);
            an = mfma16(av, *(const h8*)(bpn + (size_t)k * 512), an);
          }
          float bhr = P.b_hh[colr], bhz = P.b_hh[colr + 512], bhn = P.b_hh[colr + 1024];
#pragma unroll
          for (int j = 0; j < 4; ++j) {
            int row = m3 + q * 4 + j;
            size_t g3 = (size_t)row * GG3 + colr;
            float xr = P.GX[g3], xz = P.GX[g3 + 512], xn = P.GX[g3 + 1024];
            float rg = 1.f / (1.f + expf(-(xr + ar[j] + bhr)));
            float zg = 1.f / (1.f + expf(-(xz + az[j] + bhz)));
            float ng = tanhf(xn + rg * (an[j] + bhn));
            float ho = HFo[(size_t)row * HSZ + colr];
            P.HGRU[(size_t)row * HSZ + colr] = (1.f - zg) * ng + zg * ho;
          }
        }
      }
    }
    gbar(P.BAR, ++ep);
  }

  // ---------------- Epilogue ----------------
  // E1: update(255) -> c(255) f16 (COMlo), h(255) f16/f32
  {
    const int s = SLEN - 1;
    const float* CFo = P.CF[(s + 1) & 1];
    const float* HFo = P.HF[(s + 1) & 1];
    const float* NFo = P.NF[(s + 1) & 1];
    float* HFn = P.HF[s & 1];
    {
      int rl = tid >> 4, sg = tid & 15;
      int row = m0 + rl;
      float v = P.PART[(size_t)(sg * 4 + 0) * BSZ + row]
              + P.PART[(size_t)(sg * 4 + 1) * BSZ + row]
              + P.PART[(size_t)(sg * 4 + 2) * BSZ + row]
              + P.PART[(size_t)(sg * 4 + 3) * BSZ + row];
      v += __shfl_xor(v, 1); v += __shfl_xor(v, 2);
      v += __shfl_xor(v, 4); v += __shfl_xor(v, 8);
      if (sg == 0) {
        float lg = (v + P.b4[0] + P.LOGI[(size_t)s * BSZ + row]) * 10.0f;
        float al = 1.f / (1.f + expf(-lg));
        float om = 1.f - al;
        float no = NFo[row];
        sA[rl] = al; sNOM[rl] = no * om; sNN[rl] = no * om + 1.f;
      }
    }
    __syncthreads();
    if (cg == 0) {
      for (int e = tid; e < 16 * 512; e += 256) {
        int rl = e >> 9, col = e & 511;
        int row = m0 + rl;
        size_t go = (size_t)row * HSZ + col;
        float al = sA[rl];
        float hn = HFo[go] * (1.f - al) + al * P.HGRU[go];
        float cn = (CFo[go] * sNOM[rl]
                    + (float)P.CIN[((size_t)s * BSZ + row) * HSZ + col]) / sNN[rl];
        HFn[go] = hn;
        P.HF16[go]  = (_Float16)hn;
        P.COMlo[go] = (_Float16)cn;
      }
    }
  }
  gbar(P.BAR, ++ep);

  // E2: GX = c(255) @ W_ih + b_ih
  for (int item = gw; item < 768; item += 512) {
    int ct2 = item % 96, rt2 = item / 96;
    int m2 = rt2 << 4, col = (ct2 << 4) + ml;
    const _Float16* a0 = P.COMlo + (size_t)(m2 + ml) * HSZ + q * 8;
    const _Float16* bp = P.FWih + (size_t)ct2 * 16 * 512 + (size_t)lane * 8;
    f4 acc = {0.f, 0.f, 0.f, 0.f};
#pragma unroll
    for (int k = 0; k < 16; ++k)
      acc = mfma16(*(const h8*)(a0 + k * 32), *(const h8*)(bp + (size_t)k * 512), acc);
    float bia = P.b_ih[col];
#pragma unroll
    for (int j = 0; j < 4; ++j)
      P.GX[(size_t)(m2 + q * 4 + j) * GG3 + col] = acc[j] + bia;
  }
  gbar(P.BAR, ++ep);

  // E3: gh triples -> h_fin into HGRU
  {
    const float* HFo = P.HF[(SLEN - 1) & 1];   // h(255)
    for (int item = gw; item < 256; item += 512) {
      int tc = item & 31, rt3 = item >> 5;
      int m3 = rt3 << 4, colr = (tc << 4) + ml;
      const _Float16* a0  = P.HF16 + (size_t)(m3 + ml) * HSZ + q * 8;
      const _Float16* bpr = P.FWhh + (size_t)tc * 16 * 512 + (size_t)lane * 8;
      const _Float16* bpz = P.FWhh + (size_t)(tc + 32) * 16 * 512 + (size_t)lane * 8;
      const _Float16* bpn = P.FWhh + (size_t)(tc + 64) * 16 * 512 + (size_t)lane * 8;
      f4 ar = {0.f, 0.f, 0.f, 0.f}, az = ar, an = ar;
#pragma unroll
      for (int k = 0; k < 16; ++k) {
        h8 av = *(const h8*)(a0 + k * 32);
        ar = mfma16(av, *(const h8*)(bpr + (size_t)k * 512), ar);
        az = mfma16(av, *(const h8*)(bpz + (size_t)k * 512), az);
        an = mfma16(av, *(const h8*)(bpn + (size_t)k * 512), an);
      }
      float bhr = P.b_hh[colr], bhz = P.b_hh[colr + 512], bhn = P.b_hh[colr + 1024];
#pragma unroll
      for (int j = 0; j < 4; ++j) {
        int row = m3 + q * 4 + j;
        size_t g3 = (size_t)row * GG3 + colr;
        float xr = P.GX[g3], xz = P.GX[g3 + 512], xn = P.GX[g3 + 1024];
        float rg = 1.f / (1.f + expf(-(xr + ar[j] + bhr)));
        float zg = 1.f / (1.f + expf(-(xz + az[j] + bhz)));
        float ng = tanhf(xn + rg * (an[j] + bhn));
        float ho = HFo[(size_t)row * HSZ + colr];
        P.HGRU[(size_t)row * HSZ + colr] = (1.f - zg) * ng + zg * ho;
      }
    }
  }
  gbar(P.BAR, ++ep);

  // E4: out[row b] = h_fin @ w_out + b_out
  {
    __shared__ float hfl[512];
    const float* hsrc = P.HGRU + (size_t)b * HSZ;
    for (int e = tid; e < 512; e += 256) hfl[e] = hsrc[e];
    __syncthreads();
    for (int c2 = wv; c2 < OSZ; c2 += 4) {
      float v = 0.f;
#pragma unroll
      for (int j = 0; j < 8; ++j)
        v += hfl[lane + 64 * j] * P.w_out[(size_t)(lane + 64 * j) * OSZ + c2];
      for (int off = 32; off > 0; off >>= 1) v += __shfl_xor(v, off);
      if (lane == 0) P.out[b * OSZ + c2] = v + P.b_out[c2];
    }
  }
}

// ---------------- host ----------------
extern "C" void kernel_launch(void* const* d_in, const int* in_sizes, int n_in,
                              void* d_out, int out_size, void* d_ws, size_t ws_size,
                              hipStream_t stream) {
  const float* x     = (const float*)d_in[0];
  const float* noise = (const float*)d_in[1];
  const float* w_cin = (const float*)d_in[2];
  const float* b_cin = (const float*)d_in[3];
  const float* w1    = (const float*)d_in[4];
  const float* b1    = (const float*)d_in[5];
  const float* w2    = (const float*)d_in[6];
  const float* b2    = (const float*)d_in[7];
  const float* w3    = (const float*)d_in[8];
  const float* b3    = (const float*)d_in[9];
  const float* w4    = (const float*)d_in[10];
  const float* b4    = (const float*)d_in[11];
  const float* w_ih  = (const float*)d_in[12];
  const float* b_ih  = (const float*)d_in[13];
  const float* w_hh  = (const float*)d_in[14];
  const float* b_hh  = (const float*)d_in[15];
  const float* w_out = (const float*)d_in[16];
  const float* b_out = (const float*)d_in[17];

  char* ws = (char*)d_ws;
  size_t off = 0;
  auto alloc = [&](size_t bytes) -> void* {
    void* p = ws + off;
    off = (off + bytes + 255) & ~(size_t)255;
    return p;
  };

  P_t P;
  P.x = x; P.noise = noise; P.b_cin = b_cin; P.b1 = b1; P.b2 = b2; P.b3 = b3;
  P.w4 = w4; P.b4 = b4; P.b_ih = b_ih; P.b_hh = b_hh; P.w_out = w_out; P.b_out = b_out;
  P.WT1   = (_Float16*)alloc((size_t)HH2 * HH2 * 2);
  P.WT2   = (_Float16*)alloc((size_t)HH2 * HH2 * 2);
  P.WT3   = (_Float16*)alloc((size_t)HH2 * HH2 * 2);
  P.WTih  = (_Float16*)alloc((size_t)GG3 * HSZ * 2);
  P.WThh  = (_Float16*)alloc((size_t)GG3 * HSZ * 2);
  P.WTcin = (_Float16*)alloc((size_t)HSZ * DIN * 2);
  P.FW1   = (_Float16*)alloc((size_t)HH2 * HH2 * 2);
  P.FW2   = (_Float16*)alloc((size_t)HH2 * HH2 * 2);
  P.FW3   = (_Float16*)alloc((size_t)HH2 * HH2 * 2);
  P.FWih  = (_Float16*)alloc((size_t)GG3 * HSZ * 2);
  P.FWhh  = (_Float16*)alloc((size_t)GG3 * HSZ * 2);
  P.CIN   = (_Float16*)alloc((size_t)SLEN * BSZ * HSZ * 2);
  P.COMlo = (_Float16*)alloc((size_t)BSZ * HSZ * 2);
  P.Z1    = (_Float16*)alloc((size_t)BSZ * HH2 * 2);
  P.Z2    = (_Float16*)alloc((size_t)BSZ * HH2 * 2);
  P.HF16  = (_Float16*)alloc((size_t)BSZ * HSZ * 2);
  P.LOGI  = (float*)alloc((size_t)SLEN * BSZ * 4);
  P.GX    = (float*)alloc((size_t)BSZ * GG3 * 4);
  P.PART  = (float*)alloc((size_t)64 * BSZ * 4);
  P.HGRU  = (float*)alloc((size_t)BSZ * HSZ * 4);
  P.CF[0] = (float*)alloc((size_t)BSZ * HSZ * 4);
  P.CF[1] = (float*)alloc((size_t)BSZ * HSZ * 4);
  P.HF[0] = (float*)alloc((size_t)BSZ * HSZ * 4);
  P.HF[1] = (float*)alloc((size_t)BSZ * HSZ * 4);
  P.NF[0] = (float*)alloc((size_t)BSZ * 4);
  P.NF[1] = (float*)alloc((size_t)BSZ * 4);
  P.BAR   = (int*)alloc(2048 * 4);
  P.out   = (float*)d_out;

  transpose_cvt<<<(HH2/32)*(HH2/32), 256, 0, stream>>>(w1, P.WT1, HH2, HH2);
  transpose_cvt<<<(HH2/32)*(HH2/32), 256, 0, stream>>>(w2, P.WT2, HH2, HH2);
  transpose_cvt<<<(HH2/32)*(HH2/32), 256, 0, stream>>>(w3, P.WT3, HH2, HH2);
  transpose_cvt<<<(GG3/32)*(HSZ/32), 256, 0, stream>>>(w_ih, P.WTih, HSZ, GG3);
  transpose_cvt<<<(GG3/32)*(HSZ/32), 256, 0, stream>>>(w_hh, P.WThh, HSZ, GG3);
  transpose_cvt<<<(HSZ/32)*(DIN/32), 256, 0, stream>>>(w_cin, P.WTcin, DIN, HSZ);
  fragpack<<<HH2/16, 512, 0, stream>>>(P.WT1, P.FW1, HH2);
  fragpack<<<HH2/16, 512, 0, stream>>>(P.WT2, P.FW2, HH2);
  fragpack<<<HH2/16, 512, 0, stream>>>(P.WT3, P.FW3, HH2);
  fragpack<<<GG3/16, 512, 0, stream>>>(P.WTih, P.FWih, HSZ);
  fragpack<<<GG3/16, 512, 0, stream>>>(P.WThh, P.FWhh, HSZ);

  cin_kernel<<<1024, 256, 0, stream>>>(P);
  init_kernel<<<256, 256, 0, stream>>>(P);

  loop_kernel<<<NWG, 256, 0, stream>>>(P);
}